// Round 1
// baseline (2429.685 us; speedup 1.0000x reference)
//
#include <hip/hip_runtime.h>
#include <math.h>

#define F_IN 128
#define D 256
#define H 4
#define C 64
#define NEG_SLOPE 0.2f

// ---------------- helpers ----------------
__device__ __forceinline__ float waveReduceSum(float v) {
#pragma unroll
  for (int off = 32; off > 0; off >>= 1) v += __shfl_xor(v, off, 64);
  return v;
}

// float atomic max via int punning (works for mixed signs, init -inf)
__device__ __forceinline__ void atomicMaxFloat(float* addr, float val) {
  if (val >= 0.f) {
    atomicMax((int*)addr, __float_as_int(val));
  } else {
    atomicMin((unsigned int*)addr, (unsigned int)__float_as_int(val));
  }
}

// ---------------- generic fp32 tiled GEMM: C[M,Ncol] = A[M,K] @ B[K,Ncol] ----------------
#define BM 64
#define BN 64
#define BK 16

__global__ __launch_bounds__(256) void gemm_tiled(
    const float* __restrict__ A, const float* __restrict__ B,
    float* __restrict__ Cmat, int M, int K, int Ncol) {
  __shared__ float As[BK][BM + 4];  // +4 pad: conflict-free staging + 16B-aligned rows
  __shared__ float Bs[BK][BN];

  const int t = threadIdx.x;
  const int bm = blockIdx.x * BM;
  const int bn = blockIdx.y * BN;
  const int tm = (t >> 4) * 4;  // row offset in tile (0..60)
  const int tn = (t & 15) * 4;  // col offset in tile (0..60)

  float acc[4][4] = {};

  for (int k0 = 0; k0 < K; k0 += BK) {
    // A tile: 64 rows x 16 k; one float4 along k per thread
    {
      int m = t >> 2;
      int kk = (t & 3) * 4;
      int row = bm + m;
      if (row >= M) row = M - 1;  // clamp; stores guarded below
      const float4 av = *(const float4*)&A[(size_t)row * K + k0 + kk];
      As[kk + 0][m] = av.x;
      As[kk + 1][m] = av.y;
      As[kk + 2][m] = av.z;
      As[kk + 3][m] = av.w;
    }
    // B tile: 16 k x 64 n; one float4 along n per thread
    {
      int k = t >> 4;
      int n4 = (t & 15) * 4;
      const float4 bv = *(const float4*)&B[(size_t)(k0 + k) * Ncol + bn + n4];
      *(float4*)&Bs[k][n4] = bv;
    }
    __syncthreads();

#pragma unroll
    for (int k = 0; k < BK; ++k) {
      const float4 a = *(const float4*)&As[k][tm];
      const float4 b = *(const float4*)&Bs[k][tn];
      acc[0][0] += a.x * b.x; acc[0][1] += a.x * b.y; acc[0][2] += a.x * b.z; acc[0][3] += a.x * b.w;
      acc[1][0] += a.y * b.x; acc[1][1] += a.y * b.y; acc[1][2] += a.y * b.z; acc[1][3] += a.y * b.w;
      acc[2][0] += a.z * b.x; acc[2][1] += a.z * b.y; acc[2][2] += a.z * b.z; acc[2][3] += a.z * b.w;
      acc[3][0] += a.w * b.x; acc[3][1] += a.w * b.y; acc[3][2] += a.w * b.z; acc[3][3] += a.w * b.w;
    }
    __syncthreads();
  }

#pragma unroll
  for (int i = 0; i < 4; ++i) {
    int row = bm + tm + i;
    if (row < M) {
      float4 v = make_float4(acc[i][0], acc[i][1], acc[i][2], acc[i][3]);
      *(float4*)&Cmat[(size_t)row * Ncol + bn + tn] = v;
    }
  }
}

// ---------------- attention logits: al[n,h] = dot(hbuf[n,h,:], a[h,:]) ----------------
__global__ __launch_bounds__(256) void logits_kernel(
    const float* __restrict__ h, const float* __restrict__ a_src,
    const float* __restrict__ a_dst, float* __restrict__ al_src,
    float* __restrict__ al_dst) {
  const int n = blockIdx.x;
  const int wave = threadIdx.x >> 6;  // head
  const int lane = threadIdx.x & 63;  // channel
  const float hv = h[(size_t)n * D + wave * C + lane];
  const float s = waveReduceSum(hv * a_src[wave * C + lane]);
  const float d = waveReduceSum(hv * a_dst[wave * C + lane]);
  if (lane == 0) {
    al_src[n * H + wave] = s;
    al_dst[n * H + wave] = d;
  }
}

// ---------------- init m=-inf, denom=0 ----------------
__global__ void init_md_kernel(float* __restrict__ m, float* __restrict__ dn, int n) {
  int i = blockIdx.x * 256 + threadIdx.x;
  if (i < n) {
    m[i] = -INFINITY;
    dn[i] = 0.f;
  }
}

__global__ void zero_kernel(float4* __restrict__ p, int n4) {
  int i = blockIdx.x * 256 + threadIdx.x;
  const int stride = gridDim.x * 256;
  for (; i < n4; i += stride) p[i] = make_float4(0.f, 0.f, 0.f, 0.f);
}

// ---------------- edge pass 1: segment max ----------------
__global__ void edge_max_kernel(const int* __restrict__ ei, int E, int N,
                                const float* __restrict__ al_src,
                                const float* __restrict__ al_dst,
                                float* __restrict__ m) {
  const int e = blockIdx.x * blockDim.x + threadIdx.x;
  const int Etot = E + N;
  if (e >= Etot) return;
  int s, d;
  if (e < E) { s = ei[e]; d = ei[E + e]; } else { s = d = e - E; }
  float va[4], vd[4];
  *(float4*)va = *(const float4*)&al_src[s * 4];
  *(float4*)vd = *(const float4*)&al_dst[d * 4];
#pragma unroll
  for (int hd = 0; hd < 4; ++hd) {
    float x = va[hd] + vd[hd];
    x = (x >= 0.f) ? x : NEG_SLOPE * x;
    atomicMaxFloat(&m[d * 4 + hd], x);
  }
}

// ---------------- edge pass 2: segment sum of exp ----------------
__global__ void edge_denom_kernel(const int* __restrict__ ei, int E, int N,
                                  const float* __restrict__ al_src,
                                  const float* __restrict__ al_dst,
                                  const float* __restrict__ m,
                                  float* __restrict__ dn) {
  const int e = blockIdx.x * blockDim.x + threadIdx.x;
  const int Etot = E + N;
  if (e >= Etot) return;
  int s, d;
  if (e < E) { s = ei[e]; d = ei[E + e]; } else { s = d = e - E; }
  float va[4], vd[4], vm[4];
  *(float4*)va = *(const float4*)&al_src[s * 4];
  *(float4*)vd = *(const float4*)&al_dst[d * 4];
  *(float4*)vm = *(const float4*)&m[d * 4];
#pragma unroll
  for (int hd = 0; hd < 4; ++hd) {
    float x = va[hd] + vd[hd];
    x = (x >= 0.f) ? x : NEG_SLOPE * x;
    atomicAdd(&dn[d * 4 + hd], __expf(x - vm[hd]));
  }
}

// ---------------- edge pass 3: weighted aggregation ----------------
__global__ __launch_bounds__(256) void aggregate_kernel(
    const int* __restrict__ ei, int E, int N,
    const float* __restrict__ al_src, const float* __restrict__ al_dst,
    const float* __restrict__ m, const float* __restrict__ dn,
    const float* __restrict__ h, float* __restrict__ out) {
  const int e = blockIdx.x;
  int s, d;
  if (e < E) { s = ei[e]; d = ei[E + e]; } else { s = d = e - E; }
  const int t = threadIdx.x;
  const int hd = t >> 6;
  float x = al_src[s * 4 + hd] + al_dst[d * 4 + hd];
  x = (x >= 0.f) ? x : NEG_SLOPE * x;
  const float alpha = __expf(x - m[d * 4 + hd]) / dn[d * 4 + hd];
  const float val = h[(size_t)s * D + t] * alpha;
  atomicAdd(&out[(size_t)d * D + t], val);
}

// ---------------- bias + ELU (in place) ----------------
__global__ void bias_elu_kernel(float* __restrict__ z, const float* __restrict__ b,
                                int total) {
  int i = blockIdx.x * 256 + threadIdx.x;
  const int stride = gridDim.x * 256;
  for (; i < total; i += stride) {
    float v = z[i] + b[i & (D - 1)];
    z[i] = (v > 0.f) ? v : expm1f(v);
  }
}

// ---------------- final scorer: out[e] = relu(P[a]+Q[b]+bs1) @ Ws2 + bs2 ----------------
__global__ __launch_bounds__(256) void score_kernel(
    const int* __restrict__ eli, int EL, const float* __restrict__ P,
    const float* __restrict__ Q, const float* __restrict__ bs1,
    const float* __restrict__ Ws2, const float* __restrict__ bs2,
    float* __restrict__ out) {
  const int e = blockIdx.x * 4 + (threadIdx.x >> 6);
  if (e >= EL) return;
  const int lane = threadIdx.x & 63;
  const int a = eli[e];
  const int b = eli[EL + e];
  float p = P[(size_t)a * C + lane] + Q[(size_t)b * C + lane] + bs1[lane];
  p = (p > 0.f) ? p : 0.f;
  const float sum = waveReduceSum(p * Ws2[lane]);
  if (lane == 0) out[e] = sum + bs2[0];
}

// ---------------- launcher ----------------
extern "C" void kernel_launch(void* const* d_in, const int* in_sizes, int n_in,
                              void* d_out, int out_size, void* d_ws, size_t ws_size,
                              hipStream_t stream) {
  const float* x   = (const float*)d_in[0];
  const int*   ei  = (const int*)d_in[1];
  const int*   eli = (const int*)d_in[2];
  const float* W1  = (const float*)d_in[3];
  const float* as1 = (const float*)d_in[4];
  const float* ad1 = (const float*)d_in[5];
  const float* b1  = (const float*)d_in[6];
  const float* W2  = (const float*)d_in[7];
  const float* as2 = (const float*)d_in[8];
  const float* ad2 = (const float*)d_in[9];
  const float* b2  = (const float*)d_in[10];
  const float* Ws1 = (const float*)d_in[11];
  const float* bs1 = (const float*)d_in[12];
  const float* Ws2 = (const float*)d_in[13];
  const float* bs2 = (const float*)d_in[14];

  const int N = in_sizes[0] / F_IN;
  const int E = in_sizes[1] / 2;
  const int EL = in_sizes[2] / 2;
  const int Etot = E + N;

  float* bufA = (float*)d_ws;                    // N*D  (h of current layer / P,Q)
  float* bufB = bufA + (size_t)N * D;            // N*D  (aggregation out / z)
  float* al_src = bufB + (size_t)N * D;          // N*H
  float* al_dst = al_src + (size_t)N * H;        // N*H
  float* mbuf = al_dst + (size_t)N * H;          // N*H
  float* dbuf = mbuf + (size_t)N * H;            // N*H

  const int mdBlocks = (N * H + 255) / 256;
  const int edgeBlocks = (Etot + 255) / 256;
  const dim3 gemmGridD((N + BM - 1) / BM, D / BN);
  const dim3 gemmGridC((N + BM - 1) / BM, C / BN);

  // ---- layer 1: h1 = x @ W1 (bufA); aggregate -> bufB; elu(+b1) ----
  gemm_tiled<<<gemmGridD, 256, 0, stream>>>(x, W1, bufA, N, F_IN, D);
  logits_kernel<<<N, 256, 0, stream>>>(bufA, as1, ad1, al_src, al_dst);
  init_md_kernel<<<mdBlocks, 256, 0, stream>>>(mbuf, dbuf, N * H);
  zero_kernel<<<3200, 256, 0, stream>>>((float4*)bufB, N * D / 4);
  edge_max_kernel<<<edgeBlocks, 256, 0, stream>>>(ei, E, N, al_src, al_dst, mbuf);
  edge_denom_kernel<<<edgeBlocks, 256, 0, stream>>>(ei, E, N, al_src, al_dst, mbuf, dbuf);
  aggregate_kernel<<<Etot, 256, 0, stream>>>(ei, E, N, al_src, al_dst, mbuf, dbuf, bufA, bufB);
  bias_elu_kernel<<<3200, 256, 0, stream>>>(bufB, b1, N * D);

  // ---- layer 2: h2 = z1 @ W2 (bufA); aggregate -> bufB; elu(+b2) ----
  gemm_tiled<<<gemmGridD, 256, 0, stream>>>(bufB, W2, bufA, N, D, D);
  logits_kernel<<<N, 256, 0, stream>>>(bufA, as2, ad2, al_src, al_dst);
  init_md_kernel<<<mdBlocks, 256, 0, stream>>>(mbuf, dbuf, N * H);
  zero_kernel<<<3200, 256, 0, stream>>>((float4*)bufB, N * D / 4);
  edge_max_kernel<<<edgeBlocks, 256, 0, stream>>>(ei, E, N, al_src, al_dst, mbuf);
  edge_denom_kernel<<<edgeBlocks, 256, 0, stream>>>(ei, E, N, al_src, al_dst, mbuf, dbuf);
  aggregate_kernel<<<Etot, 256, 0, stream>>>(ei, E, N, al_src, al_dst, mbuf, dbuf, bufA, bufB);
  bias_elu_kernel<<<3200, 256, 0, stream>>>(bufB, b2, N * D);

  // ---- scorer: P = z2 @ Ws1[:256], Q = z2 @ Ws1[256:]; per-edge reduce ----
  float* P = bufA;                 // N*C
  float* Q = bufA + (size_t)N * C; // N*C
  gemm_tiled<<<gemmGridC, 256, 0, stream>>>(bufB, Ws1, P, N, D, C);
  gemm_tiled<<<gemmGridC, 256, 0, stream>>>(bufB, Ws1 + (size_t)D * C, Q, N, D, C);
  score_kernel<<<(EL + 3) / 4, 256, 0, stream>>>(eli, EL, P, Q, bs1, Ws2, bs2, (float*)d_out);
}

// Round 2
// 777.820 us; speedup vs baseline: 3.1237x; 3.1237x over previous
//
#include <hip/hip_runtime.h>
#include <math.h>

#define F_IN 128
#define D 256
#define H 4
#define C 64
#define NEG_SLOPE 0.2f
#define CH 64  // LDS chunk for aggregation

// ---------------- helpers ----------------
__device__ __forceinline__ float waveReduceSum(float v) {
#pragma unroll
  for (int off = 32; off > 0; off >>= 1) v += __shfl_xor(v, off, 64);
  return v;
}
__device__ __forceinline__ float waveReduceMax(float v) {
#pragma unroll
  for (int off = 32; off > 0; off >>= 1) v = fmaxf(v, __shfl_xor(v, off, 64));
  return v;
}
__device__ __forceinline__ float leaky(float x) {
  return (x >= 0.f) ? x : NEG_SLOPE * x;
}

// ---------------- generic fp32 tiled GEMM: C[M,Ncol] = A[M,K] @ B[K,Ncol] ----------------
#define BM 64
#define BN 64
#define BK 16

__global__ __launch_bounds__(256) void gemm_tiled(
    const float* __restrict__ A, const float* __restrict__ B,
    float* __restrict__ Cmat, int M, int K, int Ncol) {
  __shared__ float As[BK][BM + 4];
  __shared__ float Bs[BK][BN];

  const int t = threadIdx.x;
  const int bm = blockIdx.x * BM;
  const int bn = blockIdx.y * BN;
  const int tm = (t >> 4) * 4;
  const int tn = (t & 15) * 4;

  float acc[4][4] = {};

  for (int k0 = 0; k0 < K; k0 += BK) {
    {
      int m = t >> 2;
      int kk = (t & 3) * 4;
      int row = bm + m;
      if (row >= M) row = M - 1;
      const float4 av = *(const float4*)&A[(size_t)row * K + k0 + kk];
      As[kk + 0][m] = av.x;
      As[kk + 1][m] = av.y;
      As[kk + 2][m] = av.z;
      As[kk + 3][m] = av.w;
    }
    {
      int k = t >> 4;
      int n4 = (t & 15) * 4;
      const float4 bv = *(const float4*)&B[(size_t)(k0 + k) * Ncol + bn + n4];
      *(float4*)&Bs[k][n4] = bv;
    }
    __syncthreads();

#pragma unroll
    for (int k = 0; k < BK; ++k) {
      const float4 a = *(const float4*)&As[k][tm];
      const float4 b = *(const float4*)&Bs[k][tn];
      acc[0][0] += a.x * b.x; acc[0][1] += a.x * b.y; acc[0][2] += a.x * b.z; acc[0][3] += a.x * b.w;
      acc[1][0] += a.y * b.x; acc[1][1] += a.y * b.y; acc[1][2] += a.y * b.z; acc[1][3] += a.y * b.w;
      acc[2][0] += a.z * b.x; acc[2][1] += a.z * b.y; acc[2][2] += a.z * b.z; acc[2][3] += a.z * b.w;
      acc[3][0] += a.w * b.x; acc[3][1] += a.w * b.y; acc[3][2] += a.w * b.z; acc[3][3] += a.w * b.w;
    }
    __syncthreads();
  }

#pragma unroll
  for (int i = 0; i < 4; ++i) {
    int row = bm + tm + i;
    if (row < M) {
      float4 v = make_float4(acc[i][0], acc[i][1], acc[i][2], acc[i][3]);
      *(float4*)&Cmat[(size_t)row * Ncol + bn + tn] = v;
    }
  }
}

// ---------------- attention logits ----------------
__global__ __launch_bounds__(256) void logits_kernel(
    const float* __restrict__ h, const float* __restrict__ a_src,
    const float* __restrict__ a_dst, float* __restrict__ al_src,
    float* __restrict__ al_dst) {
  const int n = blockIdx.x;
  const int wave = threadIdx.x >> 6;
  const int lane = threadIdx.x & 63;
  const float hv = h[(size_t)n * D + wave * C + lane];
  const float s = waveReduceSum(hv * a_src[wave * C + lane]);
  const float d = waveReduceSum(hv * a_dst[wave * C + lane]);
  if (lane == 0) {
    al_src[n * H + wave] = s;
    al_dst[n * H + wave] = d;
  }
}

// ---------------- CSR build ----------------
__global__ void hist_kernel(const int* __restrict__ ei, int E, int N,
                            int* __restrict__ count) {
  const int e = blockIdx.x * blockDim.x + threadIdx.x;
  if (e >= E + N) return;
  const int d = (e < E) ? ei[E + e] : (e - E);
  atomicAdd(&count[d], 1);
}

// exclusive scan of one 256-block; blockSums optional
__global__ __launch_bounds__(256) void scan_block(const int* __restrict__ in,
                                                  int* __restrict__ out,
                                                  int* __restrict__ blockSums, int n) {
  const int i = blockIdx.x * 256 + threadIdx.x;
  const int lane = threadIdx.x & 63;
  const int wid = threadIdx.x >> 6;
  const int val = (i < n) ? in[i] : 0;
  int incl = val;
#pragma unroll
  for (int off = 1; off < 64; off <<= 1) {
    int m = __shfl_up(incl, off, 64);
    if (lane >= off) incl += m;
  }
  __shared__ int wsum[4], woff[5];
  if (lane == 63) wsum[wid] = incl;
  __syncthreads();
  if (threadIdx.x == 0) {
    int s = 0;
    for (int w = 0; w < 4; ++w) { woff[w] = s; s += wsum[w]; }
    woff[4] = s;
  }
  __syncthreads();
  if (i < n) out[i] = incl - val + woff[wid];
  if (threadIdx.x == 0 && blockSums) blockSums[blockIdx.x] = woff[4];
}

__global__ void scan_add(int* __restrict__ data, const int* __restrict__ blockOff, int n) {
  const int i = blockIdx.x * 256 + threadIdx.x;
  if (i < n) data[i] += blockOff[blockIdx.x];
}

__global__ void scatter_kernel(const int* __restrict__ ei, int E, int N,
                               const int* __restrict__ rowptr,
                               int* __restrict__ fill, int* __restrict__ esrc) {
  const int e = blockIdx.x * blockDim.x + threadIdx.x;
  if (e >= E + N) return;
  int s, d;
  if (e < E) { s = ei[e]; d = ei[E + e]; } else { s = d = e - E; }
  const int pos = rowptr[d] + atomicAdd(&fill[d], 1);
  esrc[pos] = s;
}

// ---------------- fused GAT aggregation (max + denom + weighted sum + bias + ELU) ----------------
__global__ __launch_bounds__(256) void agg_csr_kernel(
    const int* __restrict__ rowptr, const int* __restrict__ count,
    const int* __restrict__ esrc, const float* __restrict__ al_src,
    const float* __restrict__ al_dst, const float* __restrict__ h,
    const float* __restrict__ bias, float* __restrict__ out) {
  const int d = blockIdx.x;
  const int t = threadIdx.x;
  const int hd = t >> 6;
  const int lane = t & 63;
  const int base = rowptr[d];
  const int cnt = count[d];
  const float ald = al_dst[d * H + hd];

  // pass 1: per-head max over incoming edges
  float mx = -INFINITY;
  for (int i = lane; i < cnt; i += 64)
    mx = fmaxf(mx, leaky(al_src[esrc[base + i] * H + hd] + ald));
  mx = waveReduceMax(mx);

  // pass 2: per-head softmax denominator
  float sm = 0.f;
  for (int i = lane; i < cnt; i += 64)
    sm += __expf(leaky(al_src[esrc[base + i] * H + hd] + ald) - mx);
  sm = waveReduceSum(sm);
  const float inv = 1.f / sm;

  // pass 3: chunked weighted aggregation
  __shared__ int ssrc[CH];
  __shared__ float salpha[H][CH];
  float acc = 0.f;
  for (int c0 = 0; c0 < cnt; c0 += CH) {
    const int nch = min(CH, cnt - c0);
    __syncthreads();
    if (hd == 0 && lane < nch) ssrc[lane] = esrc[base + c0 + lane];
    if (lane < nch)
      salpha[hd][lane] =
          __expf(leaky(al_src[esrc[base + c0 + lane] * H + hd] + ald) - mx) * inv;
    __syncthreads();
    for (int j = 0; j < nch; ++j)
      acc += h[(size_t)ssrc[j] * D + t] * salpha[hd][j];
  }
  const float v = acc + bias[t];
  out[(size_t)d * D + t] = (v > 0.f) ? v : expm1f(v);
}

// ---------------- final scorer ----------------
__global__ __launch_bounds__(256) void score_kernel(
    const int* __restrict__ eli, int EL, const float* __restrict__ P,
    const float* __restrict__ Q, const float* __restrict__ bs1,
    const float* __restrict__ Ws2, const float* __restrict__ bs2,
    float* __restrict__ out) {
  const int e = blockIdx.x * 4 + (threadIdx.x >> 6);
  if (e >= EL) return;
  const int lane = threadIdx.x & 63;
  const int a = eli[e];
  const int b = eli[EL + e];
  float p = P[(size_t)a * C + lane] + Q[(size_t)b * C + lane] + bs1[lane];
  p = (p > 0.f) ? p : 0.f;
  const float sum = waveReduceSum(p * Ws2[lane]);
  if (lane == 0) out[e] = sum + bs2[0];
}

// ---------------- launcher ----------------
extern "C" void kernel_launch(void* const* d_in, const int* in_sizes, int n_in,
                              void* d_out, int out_size, void* d_ws, size_t ws_size,
                              hipStream_t stream) {
  const float* x   = (const float*)d_in[0];
  const int*   ei  = (const int*)d_in[1];
  const int*   eli = (const int*)d_in[2];
  const float* W1  = (const float*)d_in[3];
  const float* as1 = (const float*)d_in[4];
  const float* ad1 = (const float*)d_in[5];
  const float* b1  = (const float*)d_in[6];
  const float* W2  = (const float*)d_in[7];
  const float* as2 = (const float*)d_in[8];
  const float* ad2 = (const float*)d_in[9];
  const float* b2  = (const float*)d_in[10];
  const float* Ws1 = (const float*)d_in[11];
  const float* bs1 = (const float*)d_in[12];
  const float* Ws2 = (const float*)d_in[13];
  const float* bs2 = (const float*)d_in[14];

  const int N = in_sizes[0] / F_IN;
  const int E = in_sizes[1] / 2;
  const int EL = in_sizes[2] / 2;
  const int Etot = E + N;

  float* bufA = (float*)d_ws;                    // N*D
  float* bufB = bufA + (size_t)N * D;            // N*D
  float* al_src = bufB + (size_t)N * D;          // N*H
  float* al_dst = al_src + (size_t)N * H;        // N*H
  int* count  = (int*)(al_dst + (size_t)N * H);  // N
  int* rowptr = count + N;                       // N
  int* fill   = rowptr + N;                      // N
  int* blockSums = fill + N;                     // 256
  int* blockOff  = blockSums + 256;              // 256
  int* esrc   = blockOff + 256;                  // Etot

  const int edgeBlocks = (Etot + 255) / 256;
  const int nb = (N + 255) / 256;
  const dim3 gemmGridD((N + BM - 1) / BM, D / BN);
  const dim3 gemmGridC((N + BM - 1) / BM, C / BN);

  // ---- CSR build (shared by both layers) ----
  hipMemsetAsync(count, 0, (size_t)N * sizeof(int), stream);
  hipMemsetAsync(fill, 0, (size_t)N * sizeof(int), stream);
  hist_kernel<<<edgeBlocks, 256, 0, stream>>>(ei, E, N, count);
  scan_block<<<nb, 256, 0, stream>>>(count, rowptr, blockSums, N);
  scan_block<<<1, 256, 0, stream>>>(blockSums, blockOff, nullptr, nb);
  scan_add<<<nb, 256, 0, stream>>>(rowptr, blockOff, N);
  scatter_kernel<<<edgeBlocks, 256, 0, stream>>>(ei, E, N, rowptr, fill, esrc);

  // ---- layer 1 ----
  gemm_tiled<<<gemmGridD, 256, 0, stream>>>(x, W1, bufA, N, F_IN, D);
  logits_kernel<<<N, 256, 0, stream>>>(bufA, as1, ad1, al_src, al_dst);
  agg_csr_kernel<<<N, 256, 0, stream>>>(rowptr, count, esrc, al_src, al_dst,
                                        bufA, b1, bufB);

  // ---- layer 2 ----
  gemm_tiled<<<gemmGridD, 256, 0, stream>>>(bufB, W2, bufA, N, D, D);
  logits_kernel<<<N, 256, 0, stream>>>(bufA, as2, ad2, al_src, al_dst);
  agg_csr_kernel<<<N, 256, 0, stream>>>(rowptr, count, esrc, al_src, al_dst,
                                        bufA, b2, bufB);

  // ---- scorer ----
  float* P = bufA;
  float* Q = bufA + (size_t)N * C;
  gemm_tiled<<<gemmGridC, 256, 0, stream>>>(bufB, Ws1, P, N, D, C);
  gemm_tiled<<<gemmGridC, 256, 0, stream>>>(bufB, Ws1 + (size_t)D * C, Q, N, D, C);
  score_kernel<<<(EL + 3) / 4, 256, 0, stream>>>(eli, EL, P, Q, bs1, Ws2, bs2,
                                                 (float*)d_out);
}